// Round 1
// baseline (1671.315 us; speedup 1.0000x reference)
//
#include <hip/hip_runtime.h>
#include <stdint.h>

#define B_  32
#define T_  64
#define V_  32000
#define E_  256
#define H_  512
#define TS  63

typedef __attribute__((ext_vector_type(8))) short short8;
typedef __attribute__((ext_vector_type(4))) float floatx4;

union U16c { uint4 u; short8 s; };

__device__ __forceinline__ short8 ld8(const unsigned short* p) {
    U16c x; x.u = *(const uint4*)p; return x.s;
}

__device__ __forceinline__ unsigned short f2bf(float f) {
    union { float f; unsigned u; } v; v.f = f;
    unsigned r = v.u + 0x7FFFu + ((v.u >> 16) & 1u);
    return (unsigned short)(r >> 16);
}

// ---------------- setup: convert W_proj to bf16 ----------------
__global__ void k_cvt_wp(const float* __restrict__ wp, unsigned short* __restrict__ dst) {
    int i = blockIdx.x * blockDim.x + threadIdx.x;   // 2,048,000 threads, 8 elems each
    const float4* s = (const float4*)wp + (size_t)i * 2;
    float4 a = s[0], b = s[1];
    union { uint4 u; unsigned short h[8]; } o;
    o.h[0] = f2bf(a.x); o.h[1] = f2bf(a.y); o.h[2] = f2bf(a.z); o.h[3] = f2bf(a.w);
    o.h[4] = f2bf(b.x); o.h[5] = f2bf(b.y); o.h[6] = f2bf(b.z); o.h[7] = f2bf(b.w);
    ((uint4*)dst)[i] = o.u;
}

// ---------------- setup: W_ih/W_hh bf16, emb gather, h0 row, counters ----------------
__global__ void k_setup(const float* __restrict__ wih, const float* __restrict__ whh,
                        const float* __restrict__ embt, const int* __restrict__ trg,
                        const float* __restrict__ h0,
                        unsigned short* __restrict__ wih_bf, unsigned short* __restrict__ whh_bf,
                        unsigned short* __restrict__ emb_bf, unsigned short* __restrict__ hall,
                        unsigned* __restrict__ cnt)
{
    const int NIH = (3 * H_ * E_) / 4;   // 98304
    const int NHH = (3 * H_ * H_) / 4;   // 196608
    const int NEMB = TS * B_ * E_ / 4;   // 129024
    const int NH0 = B_ * H_ / 4;         // 4096
    int i = blockIdx.x * blockDim.x + threadIdx.x;
    if (i < NIH + NHH) {
        const float* src; unsigned short* dst; int j;
        if (i < NIH) { src = wih; dst = wih_bf; j = i; }
        else         { src = whh; dst = whh_bf; j = i - NIH; }
        float4 v = ((const float4*)src)[j];
        union { unsigned long long u; unsigned short h[4]; } o;
        o.h[0] = f2bf(v.x); o.h[1] = f2bf(v.y); o.h[2] = f2bf(v.z); o.h[3] = f2bf(v.w);
        ((unsigned long long*)dst)[j] = o.u;
        return;
    }
    i -= NIH + NHH;
    if (i < NEMB) {
        int r = i >> 6, c = i & 63;          // r = t*32+b, 64 float4 per 256-wide row
        int tt = r >> 5, b = r & 31;
        int tok = trg[b * T_ + tt];
        float4 v = ((const float4*)(embt + (size_t)tok * E_))[c];
        union { unsigned long long u; unsigned short h[4]; } o;
        o.h[0] = f2bf(v.x); o.h[1] = f2bf(v.y); o.h[2] = f2bf(v.z); o.h[3] = f2bf(v.w);
        ((unsigned long long*)(emb_bf + (size_t)r * E_))[c] = o.u;
        return;
    }
    i -= NEMB;
    if (i < NH0) {
        float4 v = ((const float4*)h0)[i];
        union { unsigned long long u; unsigned short h[4]; } o;
        o.h[0] = f2bf(v.x); o.h[1] = f2bf(v.y); o.h[2] = f2bf(v.z); o.h[3] = f2bf(v.w);
        ((unsigned long long*)hall)[i] = o.u;   // Hall step-0 rows == h0
        return;
    }
    i -= NH0;
    if (i < 64) cnt[i] = 0;
}

// ---------------- GRU recurrence: 32 blocks x 512 threads ----------------
// Block i owns h-dims [i*16, i*16+16) for ALL 32 batch rows.
// Waves 0..5: MFMA (mi = batch-half, gi = gate r/z/n). Waves 6,7 idle in MFMA phase.
__global__ __launch_bounds__(512) void k_gru(
    const unsigned short* __restrict__ whh_bf, const unsigned short* __restrict__ wih_bf,
    const unsigned short* __restrict__ emb_bf, const float* __restrict__ bih,
    const float* __restrict__ bhh, const float* __restrict__ h0,
    unsigned short* __restrict__ hall, unsigned* __restrict__ cnt)
{
    __shared__ float gh[32][52];
    __shared__ float gx[32][52];
    int blk = blockIdx.x, tid = threadIdx.x;
    int lane = tid & 63, w = tid >> 6;
    int mi = w & 1, gi = w >> 1;
    int row = lane & 15, quad = lane >> 4;
    int eb = tid >> 4, jl = tid & 15;       // elementwise: batch, local j
    int j = blk * 16 + jl;

    float bihr = bih[j],        bhhr = bhh[j];
    float bihz = bih[H_ + j],   bhhz = bhh[H_ + j];
    float bihn = bih[2*H_ + j], bhhn = bhh[2*H_ + j];
    float hcur = h0[eb * H_ + j];           // fp32 h state lives in a register

    for (int t = 0; t < TS; ++t) {
        if (w < 6) {
            floatx4 ah = {0.f, 0.f, 0.f, 0.f}, ax = {0.f, 0.f, 0.f, 0.f};
            int b_ = mi * 16 + row;                      // A-operand m = batch
            int gr = gi * H_ + blk * 16 + row;           // global weight row
            const unsigned short* hrow = hall + ((size_t)t * B_ + b_) * H_;
            const unsigned short* wrow = whh_bf + (size_t)gr * H_;
            #pragma unroll
            for (int k0 = 0; k0 < H_; k0 += 32)
                ah = __builtin_amdgcn_mfma_f32_16x16x32_bf16(
                        ld8(hrow + k0 + quad * 8), ld8(wrow + k0 + quad * 8), ah, 0, 0, 0);
            const unsigned short* erow = emb_bf + ((size_t)t * B_ + b_) * E_;
            const unsigned short* xrow = wih_bf + (size_t)gr * E_;
            #pragma unroll
            for (int k0 = 0; k0 < E_; k0 += 32)
                ax = __builtin_amdgcn_mfma_f32_16x16x32_bf16(
                        ld8(erow + k0 + quad * 8), ld8(xrow + k0 + quad * 8), ax, 0, 0, 0);
            // C/D layout: col(n)=lane&15, row(m)=quad*4+v
            int cb = mi * 16 + quad * 4;
            int cn = gi * 16 + row;
            #pragma unroll
            for (int v = 0; v < 4; ++v) { gh[cb + v][cn] = ah[v]; gx[cb + v][cn] = ax[v]; }
        }
        __syncthreads();
        {
            float xr = gx[eb][jl],      hr = gh[eb][jl];
            float xz = gx[eb][16 + jl], hz = gh[eb][16 + jl];
            float xn = gx[eb][32 + jl], hn = gh[eb][32 + jl];
            float r = 1.f / (1.f + __expf(-(xr + hr + bihr + bhhr)));
            float z = 1.f / (1.f + __expf(-(xz + hz + bihz + bhhz)));
            float nn = tanhf(xn + bihn + r * (hn + bhhn));
            hcur = (1.f - z) * nn + z * hcur;
            hall[((size_t)(t + 1) * B_ + eb) * H_ + j] = f2bf(hcur);
        }
        // agent-scope release; per-step counter barrier across 32 blocks
        __threadfence();
        __syncthreads();
        if (tid == 0) {
            __hip_atomic_fetch_add(cnt + t, 1u, __ATOMIC_ACQ_REL, __HIP_MEMORY_SCOPE_AGENT);
            while (__hip_atomic_load(cnt + t, __ATOMIC_ACQUIRE, __HIP_MEMORY_SCOPE_AGENT) < 32u) {
                __builtin_amdgcn_s_sleep(1);
            }
        }
        __syncthreads();
        __threadfence();   // acquire: invalidate caches before reading other blocks' h
    }
}

// ---------------- projection GEMM: logits = Hall @ Wp^T + b_proj ----------------
// M=2048 (64 steps x 32 batch), N=32000, K=512. 128x128 tile, 4 waves x 64x64.
__global__ __launch_bounds__(256) void k_gemm(const unsigned short* __restrict__ A,
                                              const unsigned short* __restrict__ Bm,
                                              const float* __restrict__ bias,
                                              float* __restrict__ out)
{
    __shared__ unsigned short As[128 * 40];   // row stride 40 shorts (padded)
    __shared__ unsigned short Bs[128 * 40];
    int m0 = blockIdx.x * 128, n0 = blockIdx.y * 128;
    int tid = threadIdx.x;
    int lane = tid & 63, w = tid >> 6;
    int wm = (w & 1) * 64, wn = (w >> 1) * 64;
    int row = lane & 15, quad = lane >> 4;
    floatx4 acc[4][4];
    #pragma unroll
    for (int a = 0; a < 4; ++a)
        #pragma unroll
        for (int b = 0; b < 4; ++b) acc[a][b] = (floatx4){0.f, 0.f, 0.f, 0.f};

    for (int k0 = 0; k0 < H_; k0 += 32) {
        if (k0) __syncthreads();
        #pragma unroll
        for (int cc = tid; cc < 512; cc += 256) {
            int m = cc >> 2, kc = cc & 3;
            *(uint4*)(As + m * 40 + kc * 8) =
                *(const uint4*)(A + ((size_t)(m0 + m)) * H_ + k0 + kc * 8);
            *(uint4*)(Bs + m * 40 + kc * 8) =
                *(const uint4*)(Bm + ((size_t)(n0 + m)) * H_ + k0 + kc * 8);
        }
        __syncthreads();
        short8 af[4], bf[4];
        #pragma unroll
        for (int mi2 = 0; mi2 < 4; ++mi2) {
            U16c x; x.u = *(const uint4*)(As + (wm + mi2 * 16 + row) * 40 + quad * 8);
            af[mi2] = x.s;
        }
        #pragma unroll
        for (int ni = 0; ni < 4; ++ni) {
            U16c x; x.u = *(const uint4*)(Bs + (wn + ni * 16 + row) * 40 + quad * 8);
            bf[ni] = x.s;
        }
        #pragma unroll
        for (int mi2 = 0; mi2 < 4; ++mi2)
            #pragma unroll
            for (int ni = 0; ni < 4; ++ni)
                acc[mi2][ni] = __builtin_amdgcn_mfma_f32_16x16x32_bf16(af[mi2], bf[ni], acc[mi2][ni], 0, 0, 0);
    }
    // epilogue: remap Hall row m = step*32+b -> out row b*64+step; add bias
    #pragma unroll
    for (int ni = 0; ni < 4; ++ni) {
        int n = n0 + wn + ni * 16 + row;
        float bp = bias[n];
        #pragma unroll
        for (int mi2 = 0; mi2 < 4; ++mi2) {
            #pragma unroll
            for (int v = 0; v < 4; ++v) {
                int m = m0 + wm + mi2 * 16 + quad * 4 + v;
                int orow = (m & 31) * 64 + (m >> 5);
                out[(size_t)orow * V_ + n] = acc[mi2][ni][v] + bp;
            }
        }
    }
}

// ---------------- in-place log_softmax, one block per output row ----------------
__global__ __launch_bounds__(320) void k_lsm(float* __restrict__ out)
{
    __shared__ float red[5];
    int rown = blockIdx.x;
    int t = rown & 63;
    float4* p = (float4*)(out + (size_t)rown * V_);
    int tid = threadIdx.x;
    if (t == 0) {   // out[:,0,:] = 0 (must rewrite every launch: d_out is re-poisoned)
        float4 z; z.x = z.y = z.z = z.w = 0.f;
        for (int i = tid; i < V_ / 4; i += 320) p[i] = z;
        return;
    }
    float4 v[25];
    #pragma unroll
    for (int jj = 0; jj < 25; ++jj) v[jj] = p[tid + jj * 320];
    float m = -3.4e38f;
    #pragma unroll
    for (int jj = 0; jj < 25; ++jj)
        m = fmaxf(m, fmaxf(fmaxf(v[jj].x, v[jj].y), fmaxf(v[jj].z, v[jj].w)));
    #pragma unroll
    for (int o = 32; o > 0; o >>= 1) m = fmaxf(m, __shfl_xor(m, o));
    if ((tid & 63) == 0) red[tid >> 6] = m;
    __syncthreads();
    m = fmaxf(fmaxf(fmaxf(red[0], red[1]), fmaxf(red[2], red[3])), red[4]);
    __syncthreads();
    float s = 0.f;
    #pragma unroll
    for (int jj = 0; jj < 25; ++jj)
        s += __expf(v[jj].x - m) + __expf(v[jj].y - m) + __expf(v[jj].z - m) + __expf(v[jj].w - m);
    #pragma unroll
    for (int o = 32; o > 0; o >>= 1) s += __shfl_xor(s, o);
    if ((tid & 63) == 0) red[tid >> 6] = s;
    __syncthreads();
    s = red[0] + red[1] + red[2] + red[3] + red[4];
    float lz = m + logf(s);
    #pragma unroll
    for (int jj = 0; jj < 25; ++jj) {
        float4 o4;
        o4.x = v[jj].x - lz; o4.y = v[jj].y - lz; o4.z = v[jj].z - lz; o4.w = v[jj].w - lz;
        p[tid + jj * 320] = o4;
    }
}

extern "C" void kernel_launch(void* const* d_in, const int* in_sizes, int n_in,
                              void* d_out, int out_size, void* d_ws, size_t ws_size,
                              hipStream_t stream) {
    const int*   trg   = (const int*)d_in[0];
    const float* h0    = (const float*)d_in[1];
    const float* embt  = (const float*)d_in[2];
    const float* wih   = (const float*)d_in[3];
    const float* whh   = (const float*)d_in[4];
    const float* bih   = (const float*)d_in[5];
    const float* bhh   = (const float*)d_in[6];
    const float* wproj = (const float*)d_in[7];
    const float* bproj = (const float*)d_in[8];
    float* out = (float*)d_out;

    char* ws = (char*)d_ws;
    size_t off = 0;
    unsigned short* wp_bf  = (unsigned short*)(ws + off); off += (size_t)V_ * H_ * 2;      // 32.77 MB
    unsigned short* wih_bf = (unsigned short*)(ws + off); off += (size_t)3 * H_ * E_ * 2;  // 0.79 MB
    unsigned short* whh_bf = (unsigned short*)(ws + off); off += (size_t)3 * H_ * H_ * 2;  // 1.57 MB
    unsigned short* emb_bf = (unsigned short*)(ws + off); off += (size_t)TS * B_ * E_ * 2; // 1.03 MB
    unsigned short* hall   = (unsigned short*)(ws + off); off += (size_t)64 * B_ * H_ * 2; // 2.10 MB
    unsigned*       cnt    = (unsigned*)(ws + off);       off += 256;

    k_cvt_wp<<<8000, 256, 0, stream>>>(wproj, wp_bf);                       // V*H/8 threads exact
    k_setup<<<1673, 256, 0, stream>>>(wih, whh, embt, trg, h0,
                                      wih_bf, whh_bf, emb_bf, hall, cnt);
    k_gru<<<32, 512, 0, stream>>>(whh_bf, wih_bf, emb_bf, bih, bhh, h0, hall, cnt);
    dim3 gg(16, 250);
    k_gemm<<<gg, 256, 0, stream>>>(hall, wp_bf, bproj, out);
    k_lsm<<<2048, 320, 0, stream>>>(out);
}

// Round 2
// 1161.884 us; speedup vs baseline: 1.4385x; 1.4385x over previous
//
#include <hip/hip_runtime.h>
#include <stdint.h>

#define B_  32
#define T_  64
#define V_  32000
#define E_  256
#define H_  512
#define TS  63

typedef __attribute__((ext_vector_type(8))) short short8;
typedef __attribute__((ext_vector_type(4))) float floatx4;

union U16c { uint4 u; short8 s; };

__device__ __forceinline__ short8 ld8(const unsigned short* p) {
    U16c x; x.u = *(const uint4*)p; return x.s;
}

__device__ __forceinline__ unsigned short f2bf(float f) {
    union { float f; unsigned u; } v; v.f = f;
    unsigned r = v.u + 0x7FFFu + ((v.u >> 16) & 1u);
    return (unsigned short)(r >> 16);
}

// ---------------- setup: convert W_proj to bf16 ----------------
__global__ void k_cvt_wp(const float* __restrict__ wp, unsigned short* __restrict__ dst) {
    int i = blockIdx.x * blockDim.x + threadIdx.x;   // 2,048,000 threads, 8 elems each
    const float4* s = (const float4*)wp + (size_t)i * 2;
    float4 a = s[0], b = s[1];
    union { uint4 u; unsigned short h[8]; } o;
    o.h[0] = f2bf(a.x); o.h[1] = f2bf(a.y); o.h[2] = f2bf(a.z); o.h[3] = f2bf(a.w);
    o.h[4] = f2bf(b.x); o.h[5] = f2bf(b.y); o.h[6] = f2bf(b.z); o.h[7] = f2bf(b.w);
    ((uint4*)dst)[i] = o.u;
}

// ---------------- setup: W_ih/W_hh bf16, emb gather, h0 row, counters ----------------
__global__ void k_setup(const float* __restrict__ wih, const float* __restrict__ whh,
                        const float* __restrict__ embt, const int* __restrict__ trg,
                        const float* __restrict__ h0,
                        unsigned short* __restrict__ wih_bf, unsigned short* __restrict__ whh_bf,
                        unsigned short* __restrict__ emb_bf, unsigned short* __restrict__ hall,
                        unsigned* __restrict__ cnt)
{
    const int NIH = (3 * H_ * E_) / 4;   // 98304
    const int NHH = (3 * H_ * H_) / 4;   // 196608
    const int NEMB = TS * B_ * E_ / 4;   // 129024
    const int NH0 = B_ * H_ / 4;         // 4096
    int i = blockIdx.x * blockDim.x + threadIdx.x;
    if (i < NIH + NHH) {
        const float* src; unsigned short* dst; int j;
        if (i < NIH) { src = wih; dst = wih_bf; j = i; }
        else         { src = whh; dst = whh_bf; j = i - NIH; }
        float4 v = ((const float4*)src)[j];
        union { unsigned long long u; unsigned short h[4]; } o;
        o.h[0] = f2bf(v.x); o.h[1] = f2bf(v.y); o.h[2] = f2bf(v.z); o.h[3] = f2bf(v.w);
        ((unsigned long long*)dst)[j] = o.u;
        return;
    }
    i -= NIH + NHH;
    if (i < NEMB) {
        int r = i >> 6, c = i & 63;          // r = t*32+b, 64 float4 per 256-wide row
        int tt = r >> 5, b = r & 31;
        int tok = trg[b * T_ + tt];
        float4 v = ((const float4*)(embt + (size_t)tok * E_))[c];
        union { unsigned long long u; unsigned short h[4]; } o;
        o.h[0] = f2bf(v.x); o.h[1] = f2bf(v.y); o.h[2] = f2bf(v.z); o.h[3] = f2bf(v.w);
        ((unsigned long long*)(emb_bf + (size_t)r * E_))[c] = o.u;
        return;
    }
    i -= NEMB;
    if (i < NH0) {
        float4 v = ((const float4*)h0)[i];
        union { unsigned long long u; unsigned short h[4]; } o;
        o.h[0] = f2bf(v.x); o.h[1] = f2bf(v.y); o.h[2] = f2bf(v.z); o.h[3] = f2bf(v.w);
        ((unsigned long long*)hall)[i] = o.u;   // Hall step-0 rows == h0
        return;
    }
    i -= NH0;
    if (i < 64) cnt[i] = 0;
}

// ---------------- GRU recurrence: 32 blocks x 512 threads ----------------
// Block i owns h-dims [i*16, i*16+16) for ALL 32 batch rows.
// h exchange goes through the coherent point (L3) only: RELAXED agent-scope
// atomic stores (write-through, sc0 sc1) + RELAXED atomic loads (bypass stale
// L2). NO threadfence / NO acquire-release => no L2 writeback/invalidate on
// the critical path. Ordering: __syncthreads() drains vmcnt before s_barrier.
__global__ __launch_bounds__(512) void k_gru(
    const unsigned short* __restrict__ whh_bf, const unsigned short* __restrict__ wih_bf,
    const unsigned short* __restrict__ emb_bf, const float* __restrict__ bih,
    const float* __restrict__ bhh, const float* __restrict__ h0,
    unsigned short* __restrict__ hall, unsigned* __restrict__ cnt)
{
    __shared__ unsigned short hs[32 * 528];  // 33.8 KB, stride 528 (16B-aligned rows, conflict-free b128)
    __shared__ float gh[32][52];
    __shared__ float gx[32][52];
    unsigned* hallw = (unsigned*)hall;
    int blk = blockIdx.x, tid = threadIdx.x;
    int lane = tid & 63, w = tid >> 6;
    int mi = w & 1, gi = w >> 1;
    int row = lane & 15, quad = lane >> 4;
    int eb = tid >> 4, jl = tid & 15;       // elementwise: batch, local j
    int j = blk * 16 + jl;

    float bihr = bih[j],        bhhr = bhh[j];
    float bihz = bih[H_ + j],   bhhz = bhh[H_ + j];
    float bihn = bih[2*H_ + j], bhhn = bhh[2*H_ + j];
    float hcur = h0[eb * H_ + j];           // fp32 h state lives in a register

    for (int t = 0; t < TS; ++t) {
        // ---- stage hall[t] (32x512 bf16 = 32 KB) into LDS, coherent dword loads ----
        #pragma unroll
        for (int i = 0; i < 16; ++i) {
            int idx = tid + i * 512;
            int r = idx >> 8, c = idx & 255;     // 256 dwords per 512-bf16 row
            unsigned v = __hip_atomic_load(hallw + ((size_t)t * B_ + r) * (H_ / 2) + c,
                                           __ATOMIC_RELAXED, __HIP_MEMORY_SCOPE_AGENT);
            ((unsigned*)(hs + (size_t)r * 528))[c] = v;
        }
        __syncthreads();

        if (w < 6) {
            floatx4 ah = {0.f, 0.f, 0.f, 0.f}, ax = {0.f, 0.f, 0.f, 0.f};
            int b_ = mi * 16 + row;                      // A-operand m = batch
            int gr = gi * H_ + blk * 16 + row;           // global weight row
            const unsigned short* wrow = whh_bf + (size_t)gr * H_;
            #pragma unroll
            for (int k0 = 0; k0 < H_; k0 += 32)
                ah = __builtin_amdgcn_mfma_f32_16x16x32_bf16(
                        ld8(hs + b_ * 528 + k0 + quad * 8), ld8(wrow + k0 + quad * 8), ah, 0, 0, 0);
            const unsigned short* erow = emb_bf + ((size_t)t * B_ + b_) * E_;
            const unsigned short* xrow = wih_bf + (size_t)gr * E_;
            #pragma unroll
            for (int k0 = 0; k0 < E_; k0 += 32)
                ax = __builtin_amdgcn_mfma_f32_16x16x32_bf16(
                        ld8(erow + k0 + quad * 8), ld8(xrow + k0 + quad * 8), ax, 0, 0, 0);
            // C/D layout: col(n)=lane&15, row(m)=quad*4+v
            int cb = mi * 16 + quad * 4;
            int cn = gi * 16 + row;
            #pragma unroll
            for (int v = 0; v < 4; ++v) { gh[cb + v][cn] = ah[v]; gx[cb + v][cn] = ax[v]; }
        }
        __syncthreads();
        {
            float xr = gx[eb][jl],      hr = gh[eb][jl];
            float xz = gx[eb][16 + jl], hz = gh[eb][16 + jl];
            float xn = gx[eb][32 + jl], hn = gh[eb][32 + jl];
            float r = 1.f / (1.f + __expf(-(xr + hr + bihr + bhhr)));
            float z = 1.f / (1.f + __expf(-(xz + hz + bihz + bhhz)));
            float nn = tanhf(xn + bihn + r * (hn + bhhn));
            hcur = (1.f - z) * nn + z * hcur;
            // pack pair (j even, j odd) into one dword; write-through to L3
            float hnb = __shfl_xor(hcur, 1);
            if (!(tid & 1)) {
                unsigned pk = (unsigned)f2bf(hcur) | ((unsigned)f2bf(hnb) << 16);
                __hip_atomic_store(hallw + ((size_t)(t + 1) * B_ + eb) * (H_ / 2) + (j >> 1),
                                   pk, __ATOMIC_RELAXED, __HIP_MEMORY_SCOPE_AGENT);
            }
        }
        __syncthreads();   // drains vmcnt: all coherent stores acked at L3 before flag bump
        if (tid == 0) {
            __hip_atomic_fetch_add(cnt + t, 1u, __ATOMIC_RELAXED, __HIP_MEMORY_SCOPE_AGENT);
            while (__hip_atomic_load(cnt + t, __ATOMIC_RELAXED, __HIP_MEMORY_SCOPE_AGENT) < 32u) { }
        }
        __syncthreads();
    }
}

// ---------------- projection GEMM: logits = Hall @ Wp^T + b_proj ----------------
// M=2048 (64 steps x 32 batch), N=32000, K=512. 128x128 tile, 4 waves x 64x64.
// m97-style staging: global_load_lds width=16, lane-contiguous unpadded [m][32] LDS.
__global__ __launch_bounds__(256) void k_gemm(const unsigned short* __restrict__ A,
                                              const unsigned short* __restrict__ Bm,
                                              const float* __restrict__ bias,
                                              float* __restrict__ out)
{
    __shared__ unsigned short As[128 * 32];   // 8 KB, row stride 32 shorts (64 B) — no pad
    __shared__ unsigned short Bs[128 * 32];
    int m0 = blockIdx.x * 128, n0 = blockIdx.y * 128;
    int tid = threadIdx.x;
    int lane = tid & 63, w = tid >> 6;
    int wm = (w & 1) * 64, wn = (w >> 1) * 64;
    int row = lane & 15, quad = lane >> 4;
    int srow = lane >> 2, skc = lane & 3;     // staging: lane -> (row-in-16, k-chunk)
    floatx4 acc[4][4];
    #pragma unroll
    for (int a = 0; a < 4; ++a)
        #pragma unroll
        for (int b = 0; b < 4; ++b) acc[a][b] = (floatx4){0.f, 0.f, 0.f, 0.f};

    for (int k0 = 0; k0 < H_; k0 += 32) {
        if (k0) __syncthreads();
        #pragma unroll
        for (int p = 0; p < 2; ++p) {
            int seg = w * 2 + p;              // 0..7, 16 rows each
            int m = seg * 16 + srow;
            __builtin_amdgcn_global_load_lds(
                (const __attribute__((address_space(1))) void*)(A + (size_t)(m0 + m) * H_ + k0 + skc * 8),
                (__attribute__((address_space(3))) void*)(As + seg * 512),
                16, 0, 0);
            __builtin_amdgcn_global_load_lds(
                (const __attribute__((address_space(1))) void*)(Bm + (size_t)(n0 + m) * H_ + k0 + skc * 8),
                (__attribute__((address_space(3))) void*)(Bs + seg * 512),
                16, 0, 0);
        }
        __syncthreads();
        short8 af[4], bf[4];
        #pragma unroll
        for (int mi2 = 0; mi2 < 4; ++mi2)
            af[mi2] = ld8(As + (wm + mi2 * 16 + row) * 32 + quad * 8);
        #pragma unroll
        for (int ni = 0; ni < 4; ++ni)
            bf[ni] = ld8(Bs + (wn + ni * 16 + row) * 32 + quad * 8);
        #pragma unroll
        for (int mi2 = 0; mi2 < 4; ++mi2)
            #pragma unroll
            for (int ni = 0; ni < 4; ++ni)
                acc[mi2][ni] = __builtin_amdgcn_mfma_f32_16x16x32_bf16(af[mi2], bf[ni], acc[mi2][ni], 0, 0, 0);
    }
    // epilogue: remap Hall row m = step*32+b -> out row b*64+step; add bias
    #pragma unroll
    for (int ni = 0; ni < 4; ++ni) {
        int n = n0 + wn + ni * 16 + row;
        float bp = bias[n];
        #pragma unroll
        for (int mi2 = 0; mi2 < 4; ++mi2) {
            #pragma unroll
            for (int v = 0; v < 4; ++v) {
                int m = m0 + wm + mi2 * 16 + quad * 4 + v;
                int orow = (m & 31) * 64 + (m >> 5);
                out[(size_t)orow * V_ + n] = acc[mi2][ni][v] + bp;
            }
        }
    }
}

// ---------------- in-place log_softmax, one block per output row ----------------
__global__ __launch_bounds__(320) void k_lsm(float* __restrict__ out)
{
    __shared__ float red[5];
    int rown = blockIdx.x;
    int t = rown & 63;
    float4* p = (float4*)(out + (size_t)rown * V_);
    int tid = threadIdx.x;
    if (t == 0) {   // out[:,0,:] = 0 (must rewrite every launch: d_out is re-poisoned)
        float4 z; z.x = z.y = z.z = z.w = 0.f;
        for (int i = tid; i < V_ / 4; i += 320) p[i] = z;
        return;
    }
    float4 v[25];
    #pragma unroll
    for (int jj = 0; jj < 25; ++jj) v[jj] = p[tid + jj * 320];
    float m = -3.4e38f;
    #pragma unroll
    for (int jj = 0; jj < 25; ++jj)
        m = fmaxf(m, fmaxf(fmaxf(v[jj].x, v[jj].y), fmaxf(v[jj].z, v[jj].w)));
    #pragma unroll
    for (int o = 32; o > 0; o >>= 1) m = fmaxf(m, __shfl_xor(m, o));
    if ((tid & 63) == 0) red[tid >> 6] = m;
    __syncthreads();
    m = fmaxf(fmaxf(fmaxf(red[0], red[1]), fmaxf(red[2], red[3])), red[4]);
    __syncthreads();
    float s = 0.f;
    #pragma unroll
    for (int jj = 0; jj < 25; ++jj)
        s += __expf(v[jj].x - m) + __expf(v[jj].y - m) + __expf(v[jj].z - m) + __expf(v[jj].w - m);
    #pragma unroll
    for (int o = 32; o > 0; o >>= 1) s += __shfl_xor(s, o);
    if ((tid & 63) == 0) red[tid >> 6] = s;
    __syncthreads();
    s = red[0] + red[1] + red[2] + red[3] + red[4];
    float lz = m + logf(s);
    #pragma unroll
    for (int jj = 0; jj < 25; ++jj) {
        float4 o4;
        o4.x = v[jj].x - lz; o4.y = v[jj].y - lz; o4.z = v[jj].z - lz; o4.w = v[jj].w - lz;
        p[tid + jj * 320] = o4;
    }
}

extern "C" void kernel_launch(void* const* d_in, const int* in_sizes, int n_in,
                              void* d_out, int out_size, void* d_ws, size_t ws_size,
                              hipStream_t stream) {
    const int*   trg   = (const int*)d_in[0];
    const float* h0    = (const float*)d_in[1];
    const float* embt  = (const float*)d_in[2];
    const float* wih   = (const float*)d_in[3];
    const float* whh   = (const float*)d_in[4];
    const float* bih   = (const float*)d_in[5];
    const float* bhh   = (const float*)d_in[6];
    const float* wproj = (const float*)d_in[7];
    const float* bproj = (const float*)d_in[8];
    float* out = (float*)d_out;

    char* ws = (char*)d_ws;
    size_t off = 0;
    unsigned short* wp_bf  = (unsigned short*)(ws + off); off += (size_t)V_ * H_ * 2;      // 32.77 MB
    unsigned short* wih_bf = (unsigned short*)(ws + off); off += (size_t)3 * H_ * E_ * 2;  // 0.79 MB
    unsigned short* whh_bf = (unsigned short*)(ws + off); off += (size_t)3 * H_ * H_ * 2;  // 1.57 MB
    unsigned short* emb_bf = (unsigned short*)(ws + off); off += (size_t)TS * B_ * E_ * 2; // 1.03 MB
    unsigned short* hall   = (unsigned short*)(ws + off); off += (size_t)64 * B_ * H_ * 2; // 2.10 MB
    unsigned*       cnt    = (unsigned*)(ws + off);       off += 256;

    k_cvt_wp<<<8000, 256, 0, stream>>>(wproj, wp_bf);                       // V*H/8 threads exact
    k_setup<<<1673, 256, 0, stream>>>(wih, whh, embt, trg, h0,
                                      wih_bf, whh_bf, emb_bf, hall, cnt);
    k_gru<<<32, 512, 0, stream>>>(whh_bf, wih_bf, emb_bf, bih, bhh, h0, hall, cnt);
    dim3 gg(16, 250);
    k_gemm<<<gg, 256, 0, stream>>>(hall, wp_bf, bproj, out);
    k_lsm<<<2048, 320, 0, stream>>>(out);
}